// Round 1
// baseline (168.238 us; speedup 1.0000x reference)
//
#include <hip/hip_runtime.h>

// DemandMap: site_type_map (4096x4096 int32, row-major [x][y]) ->
// out [7][2048][2048] fp32 = bin_area(4.0) - per-type demand.
//
// Geometry collapse: binW=binH=2, integer site coords, node sizes in [0,1)
// => each site overlaps exactly its home bin (x/2, y/2) with area
// ((x+nw)-x) * ((y+nh)-y)  (fp32 rounding mirrored from the JAX reference).
// Each bin gathers its 4 covered sites. Maps 0..4 replicate type-1 demand,
// map 5 = type 2, map 6 = type 3.

constexpr int NBX = 2048;
constexpr int NBY = 2048;
constexpr int H   = 4096;              // site map height (y extent)
constexpr int MAPQ = NBX * NBY / 4;    // float4 elements per output map

__global__ __launch_bounds__(256) void demand_map_kernel(
    const int*   __restrict__ st,
    const float* __restrict__ nsx,
    const float* __restrict__ nsy,
    float4*      __restrict__ out)
{
    const int tid = blockIdx.x * 256 + threadIdx.x;
    const int i   = tid >> 9;          // bin-x index (0..2047)
    const int jg  = tid & 511;         // group of 4 bins along y

    // node sizes (scalar-cached broadcast loads)
    const float nwx1 = nsx[1], nwx2 = nsx[2], nwx3 = nsx[3];
    const float nwy1 = nsy[1], nwy2 = nsy[2], nwy3 = nsy[3];

    const int   row0 = i * 2;
    const float xf0  = (float)row0;
    const float xf1  = (float)(row0 + 1);

    // per-row, per-type wx = (x + nw) - x  (reference rounding)
    const float wx0t1 = (xf0 + nwx1) - xf0, wx0t2 = (xf0 + nwx2) - xf0, wx0t3 = (xf0 + nwx3) - xf0;
    const float wx1t1 = (xf1 + nwx1) - xf1, wx1t2 = (xf1 + nwx2) - xf1, wx1t3 = (xf1 + nwx3) - xf1;

    // load 8 site types from each of the two covered rows (2 x int4 per row)
    const int4* p0 = reinterpret_cast<const int4*>(st + (size_t)row0 * H + 8 * jg);
    const int4* p1 = reinterpret_cast<const int4*>(st + ((size_t)row0 + 1) * H + 8 * jg);
    const int4 r0a = p0[0], r0b = p0[1];
    const int4 r1a = p1[0], r1b = p1[1];

    const int t0[8] = { r0a.x, r0a.y, r0a.z, r0a.w, r0b.x, r0b.y, r0b.z, r0b.w };
    const int t1[8] = { r1a.x, r1a.y, r1a.z, r1a.w, r1b.x, r1b.y, r1b.z, r1b.w };

    const int ybase = jg * 8;

    float v0[4], v5[4], v6[4];

    #pragma unroll
    for (int b = 0; b < 4; ++b) {
        float acc1 = 0.f, acc2 = 0.f, acc3 = 0.f;
        #pragma unroll
        for (int c = 0; c < 2; ++c) {
            const int   y  = ybase + 2 * b + c;
            const float yf = (float)y;
            // ---- row 0 site ----
            {
                const int t = t0[2 * b + c];
                const float nh = (t == 1) ? nwy1 : ((t == 2) ? nwy2 : nwy3);
                const float wx = (t == 1) ? wx0t1 : ((t == 2) ? wx0t2 : wx0t3);
                const float wy = (yf + nh) - yf;
                const float a  = wx * wy;
                acc1 += (t == 1) ? a : 0.f;
                acc2 += (t == 2) ? a : 0.f;
                acc3 += (t == 3) ? a : 0.f;
            }
            // ---- row 1 site ----
            {
                const int t = t1[2 * b + c];
                const float nh = (t == 1) ? nwy1 : ((t == 2) ? nwy2 : nwy3);
                const float wx = (t == 1) ? wx1t1 : ((t == 2) ? wx1t2 : wx1t3);
                const float wy = (yf + nh) - yf;
                const float a  = wx * wy;
                acc1 += (t == 1) ? a : 0.f;
                acc2 += (t == 2) ? a : 0.f;
                acc3 += (t == 3) ? a : 0.f;
            }
        }
        v0[b] = 4.0f - acc1;
        v5[b] = 4.0f - acc2;
        v6[b] = 4.0f - acc3;
    }

    const float4 V0 = { v0[0], v0[1], v0[2], v0[3] };
    const float4 V5 = { v5[0], v5[1], v5[2], v5[3] };
    const float4 V6 = { v6[0], v6[1], v6[2], v6[3] };

    const size_t obase = (size_t)i * (NBY / 4) + jg;
    #pragma unroll
    for (int m = 0; m < 5; ++m) out[(size_t)m * MAPQ + obase] = V0;  // maps 0..4 alias c0
    out[(size_t)5 * MAPQ + obase] = V5;
    out[(size_t)6 * MAPQ + obase] = V6;
}

extern "C" void kernel_launch(void* const* d_in, const int* in_sizes, int n_in,
                              void* d_out, int out_size, void* d_ws, size_t ws_size,
                              hipStream_t stream) {
    const int*   st  = (const int*)d_in[0];    // site_type_map, 4096*4096 int32
    const float* nsx = (const float*)d_in[1];  // node_size_x, 4 floats
    const float* nsy = (const float*)d_in[2];  // node_size_y, 4 floats
    float4*      out = (float4*)d_out;         // 7*2048*2048 fp32

    const int total_threads = NBX * (NBY / 4); // 2048 * 512 = 1,048,576
    const int block = 256;
    const int grid  = total_threads / block;   // 4096

    demand_map_kernel<<<grid, block, 0, stream>>>(st, nsx, nsy, out);
}